// Round 8
// baseline (189.412 us; speedup 1.0000x reference)
//
#include <hip/hip_runtime.h>
#include <hip/hip_bf16.h>

#define DFEAT   128
#define BCAP    2048         // edge capacity per 64-node bucket (avg ~1024, 32 sigma margin)
#define NB_MAX  1024

typedef __attribute__((ext_vector_type(8))) short bf16x8;
typedef __attribute__((ext_vector_type(4))) float f32x4;
typedef unsigned int uint;

// ---------------- bucket cursor init: cursor[b] = b * BCAP ----------------

__global__ void cursor_init(int* __restrict__ cursor, int NB) {
    int b = blockIdx.x * 256 + threadIdx.x;
    if (b < NB) cursor[b] = b * BCAP;
}

// ---------------- single-pass dst-bucketed edge scatter ----------------
// bucket = dst >> 6. payload: (src | dstLocal<<26, weight_bits)

__global__ __launch_bounds__(1024) void bin_scatter(const int* __restrict__ src,
                                                    const int* __restrict__ dst,
                                                    const float* __restrict__ ew,
                                                    int* __restrict__ cursor,
                                                    int2* __restrict__ bedges,
                                                    int E, int NB) {
    __shared__ int hist[NB_MAX];
    __shared__ int base[NB_MAX];
    const int tid = threadIdx.x;
    for (int b = tid; b < NB; b += 1024) hist[b] = 0;
    __syncthreads();

    int  s[8]; float w[8]; int bk[8]; int dl[8];
    const int i0 = blockIdx.x * 8192 + tid;
    #pragma unroll
    for (int k = 0; k < 8; ++k) {
        int i = i0 + k * 1024;
        if (i < E) {
            s[k] = src[i]; w[k] = ew[i];
            int d = dst[i];
            bk[k] = d >> 6; dl[k] = d & 63;
            atomicAdd(&hist[bk[k]], 1);
        } else bk[k] = -1;
    }
    __syncthreads();
    for (int b = tid; b < NB; b += 1024) {
        int c = hist[b];
        base[b] = (c > 0) ? atomicAdd(&cursor[b], c) : 0;
        hist[b] = 0;                       // reuse as rank counter
    }
    __syncthreads();
    #pragma unroll
    for (int k = 0; k < 8; ++k) {
        if (bk[k] >= 0) {
            int r = atomicAdd(&hist[bk[k]], 1);
            int pos = base[bk[k]] + r;
            if (pos < ((bk[k] + 1) << 11)) {   // overflow guard (never triggers)
                bedges[pos] = make_int2(s[k] | (dl[k] << 26), __float_as_int(w[k]));
            }
        }
    }
}

// ---------------- per-bucket LDS counting sort (in place) + rowptr/rowend ----------------

__global__ __launch_bounds__(1024) void bucket_sort(const int* __restrict__ cursor,
                                                    int2* __restrict__ bedges,
                                                    int* __restrict__ rowptr,
                                                    int* __restrict__ rowend, int N) {
    __shared__ int2 buf[BCAP];                 // 16 KB
    __shared__ int hist[64], pref[64], rank[64];
    const int b = blockIdx.x, tid = threadIdx.x;
    const int base = b << 11;                  // b * BCAP
    const int cnt = cursor[b] - base;

    if (tid < 64) hist[tid] = 0;
    __syncthreads();
    for (int i = tid; i < cnt; i += 1024) {
        int2 e = bedges[base + i];
        buf[i] = e;
        atomicAdd(&hist[((uint)e.x) >> 26], 1);
    }
    __syncthreads();
    if (tid < 64) {
        int v = hist[tid];
        int s = v;
        #pragma unroll
        for (int off = 1; off < 64; off <<= 1) {
            int t = __shfl_up(s, off, 64);
            if (tid >= off) s += t;
        }
        pref[tid] = s - v;                     // exclusive prefix
        rank[tid] = 0;
        int node = b * 64 + tid;
        if (node < N) {
            rowptr[node] = base + (s - v);
            rowend[node] = base + s;
        }
    }
    __syncthreads();
    for (int i = tid; i < cnt; i += 1024) {
        int2 e = buf[i];
        int dl = ((uint)e.x) >> 26;
        int r = atomicAdd(&rank[dl], 1);
        bedges[base + pref[dl] + r] = e;
    }
}

// ---------------- f32 -> bf16 conversion ----------------

__device__ __forceinline__ uint pack_bf16x2(float a, float b) {
    __hip_bfloat16 ba = __float2bfloat16(a);
    __hip_bfloat16 bb = __float2bfloat16(b);
    unsigned short ua = *(unsigned short*)&ba;
    unsigned short ub = *(unsigned short*)&bb;
    return (uint)ua | ((uint)ub << 16);
}

__global__ void cvt_kernel(const float* __restrict__ in, uint* __restrict__ out, int n2) {
    int i = blockIdx.x * 256 + threadIdx.x;
    if (i < n2) {
        float2 v = ((const float2*)in)[i];
        out[i] = pack_bf16x2(v.x, v.y);
    }
}

// ------------- weight pack (all 3 layers in one launch) -------------
// Bcat[k][n]: k<128 -> wrel[n][k] ; k>=128 -> wroot[n][k-128]
// Bp[((kstep*8 + nfrag)*64 + lane)*8 + j] = Bcat[kstep*32 + (lane>>4)*8 + j][nfrag*16 + (lane&15)]

__global__ void prep_Bpack3(const float* __restrict__ w1r, const float* __restrict__ w1t,
                            const float* __restrict__ w2r, const float* __restrict__ w2t,
                            const float* __restrict__ w3r, const float* __restrict__ w3t,
                            __hip_bfloat16* __restrict__ Bp1, __hip_bfloat16* __restrict__ Bp2,
                            __hip_bfloat16* __restrict__ Bp3) {
    const int g = blockIdx.x >> 7;              // 0,1,2 layer select
    const int idx = (blockIdx.x & 127) * 256 + threadIdx.x;   // 0..32767
    const float* wrel  = (g == 0) ? w1r : (g == 1) ? w2r : w3r;
    const float* wroot = (g == 0) ? w1t : (g == 1) ? w2t : w3t;
    __hip_bfloat16* Bp = (g == 0) ? Bp1 : (g == 1) ? Bp2 : Bp3;
    int j     = idx & 7;
    int lane  = (idx >> 3) & 63;
    int nfrag = (idx >> 9) & 7;
    int kstep = idx >> 12;
    int k = kstep * 32 + (lane >> 4) * 8 + j;
    int n = nfrag * 16 + (lane & 15);
    float v = (k < 128) ? wrel[n * 128 + k] : wroot[n * 128 + (k - 128)];
    Bp[idx] = __float2bfloat16(v);
}

// ---------------- aggregation: grid-stride waves, 2 nodes interleaved per wave ----------
// f: [N][16] uint4 (bf16 rows).  aggB: [N][16] uint4 bf16 agg output.
// Per node: 16 lanes/edge (grp = lane>>4 picks edge-of-quad, sub = lane&15 picks 16B slice).
// Two nodes' chains run interleaved: metadata loads back-to-back, 4 row-gathers in
// flight (2 per node) before any FMA consumption.

__global__ __launch_bounds__(256) void aggregate_bf16(const uint* __restrict__ f,
                                                      const int* __restrict__ rowptr,
                                                      const int* __restrict__ rowend,
                                                      const int2* __restrict__ bedges,
                                                      uint* __restrict__ aggB, int N) {
    const int wid = threadIdx.x >> 6, lane = threadIdx.x & 63;
    const int grp = lane >> 4;          // which edge of a quad
    const int sub = lane & 15;          // 16B slice within the row
    const int waveId = blockIdx.x * 4 + wid;
    const int nWaves = gridDim.x * 4;
    const uint4* f4 = (const uint4*)f;

    for (int nA = waveId * 2; nA < N; nA += nWaves * 2) {
        const int nB = nA + 1;
        const bool hasB = (nB < N);

        const int begA = rowptr[nA];
        const int degA = rowend[nA] - begA;
        const int begB = hasB ? rowptr[nB] : 0;
        const int degB = hasB ? (rowend[nB] - begB) : 0;

        float accA[8], accB[8];
        #pragma unroll
        for (int i = 0; i < 8; ++i) { accA[i] = 0.f; accB[i] = 0.f; }

        int doneA = 0, doneB = 0;
        while (doneA < degA || doneB < degB) {
            const int chA = min(degA - doneA, 64);
            const int chB = min(degB - doneB, 64);
            // metadata for both nodes (issued back-to-back)
            int2 eA = (chA > 0) ? bedges[begA + doneA + min(lane, chA - 1)]
                                : make_int2(0, 0);
            int2 eB = (chB > 0) ? bedges[begB + doneB + min(lane, chB - 1)]
                                : make_int2(0, 0);
            const int vsA = eA.x & 0x03FFFFFF;
            const int vwA = (lane < chA) ? eA.y : 0;    // 0 bits == 0.0f
            const int vsB = eB.x & 0x03FFFFFF;
            const int vwB = (lane < chB) ? eB.y : 0;
            const int itA = (max(chA, 0) + 7) & ~7;
            const int itB = (max(chB, 0) + 7) & ~7;
            const int iters = max(itA, itB);            // <= 64

            for (int j = 0; j < iters; j += 8) {
                // distribute metadata for 4 quads (2 per node)
                const int   sA0 = __shfl(vsA, j + grp, 64);
                const float wA0 = __int_as_float(__shfl(vwA, j + grp, 64));
                const int   sA1 = __shfl(vsA, j + 4 + grp, 64);
                const float wA1 = __int_as_float(__shfl(vwA, j + 4 + grp, 64));
                const int   sB0 = __shfl(vsB, j + grp, 64);
                const float wB0 = __int_as_float(__shfl(vwB, j + grp, 64));
                const int   sB1 = __shfl(vsB, j + 4 + grp, 64);
                const float wB1 = __int_as_float(__shfl(vwB, j + 4 + grp, 64));
                // 4 independent row-gathers in flight
                const uint4 qA0 = f4[(size_t)sA0 * 16 + sub];
                const uint4 qA1 = f4[(size_t)sA1 * 16 + sub];
                const uint4 qB0 = f4[(size_t)sB0 * 16 + sub];
                const uint4 qB1 = f4[(size_t)sB1 * 16 + sub];

                accA[0] = fmaf(wA0, __uint_as_float(qA0.x << 16),         accA[0]);
                accA[1] = fmaf(wA0, __uint_as_float(qA0.x & 0xffff0000u), accA[1]);
                accA[2] = fmaf(wA0, __uint_as_float(qA0.y << 16),         accA[2]);
                accA[3] = fmaf(wA0, __uint_as_float(qA0.y & 0xffff0000u), accA[3]);
                accA[4] = fmaf(wA0, __uint_as_float(qA0.z << 16),         accA[4]);
                accA[5] = fmaf(wA0, __uint_as_float(qA0.z & 0xffff0000u), accA[5]);
                accA[6] = fmaf(wA0, __uint_as_float(qA0.w << 16),         accA[6]);
                accA[7] = fmaf(wA0, __uint_as_float(qA0.w & 0xffff0000u), accA[7]);
                accA[0] = fmaf(wA1, __uint_as_float(qA1.x << 16),         accA[0]);
                accA[1] = fmaf(wA1, __uint_as_float(qA1.x & 0xffff0000u), accA[1]);
                accA[2] = fmaf(wA1, __uint_as_float(qA1.y << 16),         accA[2]);
                accA[3] = fmaf(wA1, __uint_as_float(qA1.y & 0xffff0000u), accA[3]);
                accA[4] = fmaf(wA1, __uint_as_float(qA1.z << 16),         accA[4]);
                accA[5] = fmaf(wA1, __uint_as_float(qA1.z & 0xffff0000u), accA[5]);
                accA[6] = fmaf(wA1, __uint_as_float(qA1.w << 16),         accA[6]);
                accA[7] = fmaf(wA1, __uint_as_float(qA1.w & 0xffff0000u), accA[7]);

                accB[0] = fmaf(wB0, __uint_as_float(qB0.x << 16),         accB[0]);
                accB[1] = fmaf(wB0, __uint_as_float(qB0.x & 0xffff0000u), accB[1]);
                accB[2] = fmaf(wB0, __uint_as_float(qB0.y << 16),         accB[2]);
                accB[3] = fmaf(wB0, __uint_as_float(qB0.y & 0xffff0000u), accB[3]);
                accB[4] = fmaf(wB0, __uint_as_float(qB0.z << 16),         accB[4]);
                accB[5] = fmaf(wB0, __uint_as_float(qB0.z & 0xffff0000u), accB[5]);
                accB[6] = fmaf(wB0, __uint_as_float(qB0.w << 16),         accB[6]);
                accB[7] = fmaf(wB0, __uint_as_float(qB0.w & 0xffff0000u), accB[7]);
                accB[0] = fmaf(wB1, __uint_as_float(qB1.x << 16),         accB[0]);
                accB[1] = fmaf(wB1, __uint_as_float(qB1.x & 0xffff0000u), accB[1]);
                accB[2] = fmaf(wB1, __uint_as_float(qB1.y << 16),         accB[2]);
                accB[3] = fmaf(wB1, __uint_as_float(qB1.y & 0xffff0000u), accB[3]);
                accB[4] = fmaf(wB1, __uint_as_float(qB1.z << 16),         accB[4]);
                accB[5] = fmaf(wB1, __uint_as_float(qB1.z & 0xffff0000u), accB[5]);
                accB[6] = fmaf(wB1, __uint_as_float(qB1.w << 16),         accB[6]);
                accB[7] = fmaf(wB1, __uint_as_float(qB1.w & 0xffff0000u), accB[7]);
            }
            doneA += max(chA, 0);
            doneB += max(chB, 0);
        }

        // combine the 4 edge-groups (lanes sharing `sub`)
        #pragma unroll
        for (int i = 0; i < 8; ++i) {
            accA[i] += __shfl_xor(accA[i], 16, 64);
            accA[i] += __shfl_xor(accA[i], 32, 64);
            accB[i] += __shfl_xor(accB[i], 16, 64);
            accB[i] += __shfl_xor(accB[i], 32, 64);
        }

        if (lane < 16) {
            uint4 oA;
            oA.x = pack_bf16x2(accA[0], accA[1]);
            oA.y = pack_bf16x2(accA[2], accA[3]);
            oA.z = pack_bf16x2(accA[4], accA[5]);
            oA.w = pack_bf16x2(accA[6], accA[7]);
            ((uint4*)aggB)[(size_t)nA * 16 + sub] = oA;
            if (hasB) {
                uint4 oB;
                oB.x = pack_bf16x2(accB[0], accB[1]);
                oB.y = pack_bf16x2(accB[2], accB[3]);
                oB.z = pack_bf16x2(accB[4], accB[5]);
                oB.w = pack_bf16x2(accB[6], accB[7]);
                ((uint4*)aggB)[(size_t)nB * 16 + sub] = oB;
            }
        }
    }
}

// ---------------- MFMA GEMM: C[M,128] = [agg|root][M,256] @ Bcat[256,128] + bias ----------
// 128x128 block tile, 4 waves (2x2), each wave 64x64 = 4x4 frags, K-loop 8 x 32.

template<int RELU, int OUTF32>
__global__ __launch_bounds__(256) void gemm_mfma(const uint* __restrict__ Aagg,
                                                 const uint* __restrict__ f,
                                                 const bf16x8* __restrict__ Bp,
                                                 const float* __restrict__ bias,
                                                 float* __restrict__ outf,
                                                 __hip_bfloat16* __restrict__ outb, int M) {
    const int tid  = threadIdx.x;
    const int lane = tid & 63, wid = tid >> 6;
    const int wr = wid >> 1, wc = wid & 1;
    const int m0 = blockIdx.x * 128 + wr * 64;
    const int n0 = wc * 64;

    f32x4 acc[4][4];
    #pragma unroll
    for (int mi = 0; mi < 4; ++mi)
        #pragma unroll
        for (int ni = 0; ni < 4; ++ni) acc[mi][ni] = (f32x4){0.f, 0.f, 0.f, 0.f};

    const short* Aa = (const short*)Aagg;
    const short* Ar = (const short*)f;
    const int lrow = lane & 15;
    const int lk   = (lane >> 4) * 8;
    int rowidx[4];
    #pragma unroll
    for (int mi = 0; mi < 4; ++mi) {
        int r = m0 + mi * 16 + lrow;
        rowidx[mi] = (r < M) ? r : (M - 1);
    }

    #pragma unroll
    for (int ks = 0; ks < 8; ++ks) {
        const short* Abase = (ks < 4) ? Aa : Ar;
        const int koff = (ks & 3) * 32 + lk;
        bf16x8 a[4], b[4];
        #pragma unroll
        for (int mi = 0; mi < 4; ++mi)
            a[mi] = *(const bf16x8*)(Abase + (size_t)rowidx[mi] * 128 + koff);
        #pragma unroll
        for (int ni = 0; ni < 4; ++ni)
            b[ni] = Bp[(ks * 8 + (wc * 4 + ni)) * 64 + lane];
        #pragma unroll
        for (int mi = 0; mi < 4; ++mi)
            #pragma unroll
            for (int ni = 0; ni < 4; ++ni)
                acc[mi][ni] = __builtin_amdgcn_mfma_f32_16x16x32_bf16(a[mi], b[ni], acc[mi][ni], 0, 0, 0);
    }

    const int crow = (lane >> 4) * 4;
    const int ccol = lane & 15;
    #pragma unroll
    for (int mi = 0; mi < 4; ++mi) {
        #pragma unroll
        for (int ni = 0; ni < 4; ++ni) {
            int col = n0 + ni * 16 + ccol;
            float bv = bias[col];
            #pragma unroll
            for (int r = 0; r < 4; ++r) {
                int row = m0 + mi * 16 + crow + r;
                if (row < M) {
                    float v = acc[mi][ni][r] + bv;
                    if (RELU) v = fmaxf(v, 0.f);
                    if (OUTF32) outf[(size_t)row * 128 + col] = v;
                    else        outb[(size_t)row * 128 + col] = __float2bfloat16(v);
                }
            }
        }
    }
}

// ---------------- launch ----------------

extern "C" void kernel_launch(void* const* d_in, const int* in_sizes, int n_in,
                              void* d_out, int out_size, void* d_ws, size_t ws_size,
                              hipStream_t stream) {
    const float* x   = (const float*)d_in[0];
    const int*  eidx = (const int*)d_in[1];
    const float* ew  = (const float*)d_in[2];
    const float* w1r = (const float*)d_in[3];
    const float* w1t = (const float*)d_in[4];
    const float* b1  = (const float*)d_in[5];
    const float* w2r = (const float*)d_in[6];
    const float* w2t = (const float*)d_in[7];
    const float* b2  = (const float*)d_in[8];
    const float* w3r = (const float*)d_in[9];
    const float* w3t = (const float*)d_in[10];
    const float* b3  = (const float*)d_in[11];
    float* out = (float*)d_out;

    const int N  = in_sizes[0] / DFEAT;   // 50000
    const int E  = in_sizes[2];           // 800000
    const int NB = (N + 63) / 64;         // 782 buckets

    char* ws = (char*)d_ws;
    size_t off = 0;
    auto alloc = [&](size_t bytes) -> void* {
        off = (off + 255) & ~(size_t)255;
        void* p = ws + off;
        off += bytes;
        return p;
    };
    int*  cursor = (int*)alloc((size_t)NB * 4);
    int*  rowptr = (int*)alloc((size_t)N * 4);
    int*  rowend = (int*)alloc((size_t)N * 4);
    int2* bedges = (int2*)alloc((size_t)NB * BCAP * 8);   // 12.8 MB
    __hip_bfloat16* Bp1 = (__hip_bfloat16*)alloc(32768 * 2);
    __hip_bfloat16* Bp2 = (__hip_bfloat16*)alloc(32768 * 2);
    __hip_bfloat16* Bp3 = (__hip_bfloat16*)alloc(32768 * 2);
    uint* xb   = (uint*)alloc((size_t)N * 64 * 4);
    uint* aggB = (uint*)alloc((size_t)N * 64 * 4);
    uint* h1b  = (uint*)alloc((size_t)N * 64 * 4);
    uint* h2b  = (uint*)alloc((size_t)N * 64 * 4);
    (void)ws_size;

    const int* src = eidx;
    const int* dst = eidx + E;

    // CSR build: bucket scatter + per-bucket counting sort
    cursor_init<<<(NB + 255) / 256, 256, 0, stream>>>(cursor, NB);
    bin_scatter<<<(E + 8191) / 8192, 1024, 0, stream>>>(src, dst, ew, cursor, bedges, E, NB);
    bucket_sort<<<NB, 1024, 0, stream>>>(cursor, bedges, rowptr, rowend, N);

    // feature + weight conversion
    cvt_kernel<<<(N * 64 + 255) / 256, 256, 0, stream>>>(x, xb, N * 64);
    prep_Bpack3<<<384, 256, 0, stream>>>(w1r, w1t, w2r, w2t, w3r, w3t, Bp1, Bp2, Bp3);

    const int aggGrid  = 1600;            // grid-stride: 6400 waves x 2 nodes
    const int gemmGrid = (N + 127) / 128;

    aggregate_bf16<<<aggGrid, 256, 0, stream>>>(xb, rowptr, rowend, bedges, aggB, N);
    gemm_mfma<1, 0><<<gemmGrid, 256, 0, stream>>>(aggB, xb, (const bf16x8*)Bp1,
                                                  b1, nullptr, (__hip_bfloat16*)h1b, N);
    aggregate_bf16<<<aggGrid, 256, 0, stream>>>(h1b, rowptr, rowend, bedges, aggB, N);
    gemm_mfma<1, 0><<<gemmGrid, 256, 0, stream>>>(aggB, h1b, (const bf16x8*)Bp2,
                                                  b2, nullptr, (__hip_bfloat16*)h2b, N);
    aggregate_bf16<<<aggGrid, 256, 0, stream>>>(h2b, rowptr, rowend, bedges, aggB, N);
    gemm_mfma<0, 1><<<gemmGrid, 256, 0, stream>>>(aggB, h2b, (const bf16x8*)Bp3,
                                                  b3, out, nullptr, N);
}

// Round 9
// 166.437 us; speedup vs baseline: 1.1380x; 1.1380x over previous
//
#include <hip/hip_runtime.h>
#include <hip/hip_bf16.h>

#define DFEAT   128
#define BCAP    2048         // edge capacity per 64-node bucket (avg ~1024, 32 sigma margin)
#define NB_MAX  1024

typedef __attribute__((ext_vector_type(8))) short bf16x8;
typedef __attribute__((ext_vector_type(4))) float f32x4;
typedef unsigned int uint;

// ---------------- single-pass dst-bucketed edge scatter ----------------
// bucket = dst >> 6. payload: (src | dstLocal<<26, weight_bits)

__global__ __launch_bounds__(1024) void bin_scatter(const int* __restrict__ src,
                                                    const int* __restrict__ dst,
                                                    const float* __restrict__ ew,
                                                    int* __restrict__ cursor,
                                                    int2* __restrict__ bedges,
                                                    int E, int NB) {
    __shared__ int hist[NB_MAX];
    __shared__ int base[NB_MAX];
    const int tid = threadIdx.x;
    for (int b = tid; b < NB; b += 1024) hist[b] = 0;
    __syncthreads();

    int  s[8]; float w[8]; int bk[8]; int dl[8];
    const int i0 = blockIdx.x * 8192 + tid;
    #pragma unroll
    for (int k = 0; k < 8; ++k) {
        int i = i0 + k * 1024;
        if (i < E) {
            s[k] = src[i]; w[k] = ew[i];
            int d = dst[i];
            bk[k] = d >> 6; dl[k] = d & 63;
            atomicAdd(&hist[bk[k]], 1);
        } else bk[k] = -1;
    }
    __syncthreads();
    for (int b = tid; b < NB; b += 1024) {
        int c = hist[b];
        base[b] = (c > 0) ? atomicAdd(&cursor[b], c) : 0;
        hist[b] = 0;                       // reuse as rank counter
    }
    __syncthreads();
    #pragma unroll
    for (int k = 0; k < 8; ++k) {
        if (bk[k] >= 0) {
            int r = atomicAdd(&hist[bk[k]], 1);
            int pos = base[bk[k]] + r;
            if (pos < ((bk[k] + 1) << 11)) {   // overflow guard (never triggers)
                bedges[pos] = make_int2(s[k] | (dl[k] << 26), __float_as_int(w[k]));
            }
        }
    }
}

// ---------------- per-bucket LDS counting sort (in place) + rowptr/rowend ----------------

__global__ __launch_bounds__(1024) void bucket_sort(const int* __restrict__ cursor,
                                                    int2* __restrict__ bedges,
                                                    int* __restrict__ rowptr,
                                                    int* __restrict__ rowend, int N) {
    __shared__ int2 buf[BCAP];                 // 16 KB
    __shared__ int hist[64], pref[64], rank[64];
    const int b = blockIdx.x, tid = threadIdx.x;
    const int base = b << 11;                  // b * BCAP
    const int cnt = cursor[b] - base;

    if (tid < 64) hist[tid] = 0;
    __syncthreads();
    for (int i = tid; i < cnt; i += 1024) {
        int2 e = bedges[base + i];
        buf[i] = e;
        atomicAdd(&hist[((uint)e.x) >> 26], 1);
    }
    __syncthreads();
    if (tid < 64) {
        int v = hist[tid];
        int s = v;
        #pragma unroll
        for (int off = 1; off < 64; off <<= 1) {
            int t = __shfl_up(s, off, 64);
            if (tid >= off) s += t;
        }
        pref[tid] = s - v;                     // exclusive prefix
        rank[tid] = 0;
        int node = b * 64 + tid;
        if (node < N) {
            rowptr[node] = base + (s - v);
            rowend[node] = base + s;
        }
    }
    __syncthreads();
    for (int i = tid; i < cnt; i += 1024) {
        int2 e = buf[i];
        int dl = ((uint)e.x) >> 26;
        int r = atomicAdd(&rank[dl], 1);
        bedges[base + pref[dl] + r] = e;
    }
}

// ---------------- helpers ----------------

__device__ __forceinline__ uint pack_bf16x2(float a, float b) {
    __hip_bfloat16 ba = __float2bfloat16(a);
    __hip_bfloat16 bb = __float2bfloat16(b);
    unsigned short ua = *(unsigned short*)&ba;
    unsigned short ub = *(unsigned short*)&bb;
    return (uint)ua | ((uint)ub << 16);
}

// ---------------- merged prep: cvt (x->bf16) + weight pack x3 + cursor init ----------------
// grid sections: [0, cvtB) cvt; [cvtB, cvtB+384) Bpack; [cvtB+384, ...) cursor init.
// Bpack: Bp[((kstep*8 + nfrag)*64 + lane)*8 + j] = Bcat[kstep*32+(lane>>4)*8+j][nfrag*16+(lane&15)]
//        where Bcat[k][n] = (k<128) ? wrel[n][k] : wroot[n][k-128]

__global__ void prep_all(const float* __restrict__ x, uint* __restrict__ xb, int n2,
                         const float* __restrict__ w1r, const float* __restrict__ w1t,
                         const float* __restrict__ w2r, const float* __restrict__ w2t,
                         const float* __restrict__ w3r, const float* __restrict__ w3t,
                         __hip_bfloat16* __restrict__ Bp1, __hip_bfloat16* __restrict__ Bp2,
                         __hip_bfloat16* __restrict__ Bp3,
                         int* __restrict__ cursor, int NB, int cvtB) {
    const int b = blockIdx.x, tid = threadIdx.x;
    if (b < cvtB) {
        int i = b * 256 + tid;
        if (i < n2) {
            float2 v = ((const float2*)x)[i];
            xb[i] = pack_bf16x2(v.x, v.y);
        }
    } else if (b < cvtB + 384) {
        const int b2 = b - cvtB;
        const int g = b2 >> 7;                       // layer 0,1,2
        const int idx = (b2 & 127) * 256 + tid;      // 0..32767
        const float* wrel  = (g == 0) ? w1r : (g == 1) ? w2r : w3r;
        const float* wroot = (g == 0) ? w1t : (g == 1) ? w2t : w3t;
        __hip_bfloat16* Bp = (g == 0) ? Bp1 : (g == 1) ? Bp2 : Bp3;
        int j     = idx & 7;
        int lane  = (idx >> 3) & 63;
        int nfrag = (idx >> 9) & 7;
        int kstep = idx >> 12;
        int k = kstep * 32 + (lane >> 4) * 8 + j;
        int n = nfrag * 16 + (lane & 15);
        float v = (k < 128) ? wrel[n * 128 + k] : wroot[n * 128 + (k - 128)];
        Bp[idx] = __float2bfloat16(v);
    } else {
        int i = (b - cvtB - 384) * 256 + tid;
        if (i < NB) cursor[i] = i * BCAP;
    }
}

// ---------------- fused layer: per-bucket agg (R7 structure) -> LDS -> MFMA GEMM ----------
// Block = one 64-node bucket, 256 threads (4 waves).
// Phase 1: wave w aggregates nodes tile+w*16 .. +15 sequentially; 16 lanes/edge
//   (grp=lane>>4 picks edge-of-quad, sub=lane&15 picks 16B row slice); result -> LDS bf16.
// Phase 2: C[64,128] = [aggLDS | root][64,256] @ Bcat[256,128] + bias via MFMA;
//   waves 2x2: wr=wid>>1 rows 32, wc=wid&1 cols 64.

template<int RELU, int OUTF32>
__global__ __launch_bounds__(256) void fused_layer(const uint* __restrict__ f,
                                                   const int* __restrict__ rowptr,
                                                   const int* __restrict__ rowend,
                                                   const int2* __restrict__ bedges,
                                                   const bf16x8* __restrict__ Bp,
                                                   const float* __restrict__ bias,
                                                   float* __restrict__ outf,
                                                   __hip_bfloat16* __restrict__ outb,
                                                   int N) {
    __shared__ uint4 As4[64][17];                  // 17408 B, row stride 272B
    const int tid  = threadIdx.x;
    const int lane = tid & 63, wid = tid >> 6;
    const int grp  = lane >> 4;
    const int sub  = lane & 15;
    const int tile = blockIdx.x * 64;
    const uint4* f4 = (const uint4*)f;

    // prefetch this wave's 16 rowptr/rowend (lane-parallel, one round-trip)
    const int pn = tile + wid * 16 + (lane & 15);
    int rp = 0, re = 0;
    if (lane < 16 && pn < N) { rp = rowptr[pn]; re = rowend[pn]; }

    // ---- phase 1: aggregate 16 nodes per wave ----
    for (int q = 0; q < 16; ++q) {
        const int node = tile + wid * 16 + q;
        const int beg = __builtin_amdgcn_readlane(rp, q);
        const int end = __builtin_amdgcn_readlane(re, q);
        const int deg = end - beg;

        float acc[8];
        #pragma unroll
        for (int i = 0; i < 8; ++i) acc[i] = 0.f;

        if (node < N) {
            int done = 0;
            while (done < deg) {
                const int chunk = min(deg - done, 64);
                int2 e = bedges[beg + done + min(lane, chunk - 1)];
                const int vsrc = e.x & 0x03FFFFFF;
                const int vwb  = (lane < chunk) ? e.y : 0;   // 0 bits == 0.0f
                const int iters = (chunk + 7) & ~7;
                for (int j = 0; j < iters; j += 8) {
                    const int   s0 = __shfl(vsrc, j + grp, 64);
                    const float w0 = __int_as_float(__shfl(vwb, j + grp, 64));
                    const int   s1 = __shfl(vsrc, j + 4 + grp, 64);
                    const float w1 = __int_as_float(__shfl(vwb, j + 4 + grp, 64));
                    const uint4 q0 = f4[(size_t)s0 * 16 + sub];
                    const uint4 q1 = f4[(size_t)s1 * 16 + sub];
                    acc[0] = fmaf(w0, __uint_as_float(q0.x << 16),         acc[0]);
                    acc[1] = fmaf(w0, __uint_as_float(q0.x & 0xffff0000u), acc[1]);
                    acc[2] = fmaf(w0, __uint_as_float(q0.y << 16),         acc[2]);
                    acc[3] = fmaf(w0, __uint_as_float(q0.y & 0xffff0000u), acc[3]);
                    acc[4] = fmaf(w0, __uint_as_float(q0.z << 16),         acc[4]);
                    acc[5] = fmaf(w0, __uint_as_float(q0.z & 0xffff0000u), acc[5]);
                    acc[6] = fmaf(w0, __uint_as_float(q0.w << 16),         acc[6]);
                    acc[7] = fmaf(w0, __uint_as_float(q0.w & 0xffff0000u), acc[7]);
                    acc[0] = fmaf(w1, __uint_as_float(q1.x << 16),         acc[0]);
                    acc[1] = fmaf(w1, __uint_as_float(q1.x & 0xffff0000u), acc[1]);
                    acc[2] = fmaf(w1, __uint_as_float(q1.y << 16),         acc[2]);
                    acc[3] = fmaf(w1, __uint_as_float(q1.y & 0xffff0000u), acc[3]);
                    acc[4] = fmaf(w1, __uint_as_float(q1.z << 16),         acc[4]);
                    acc[5] = fmaf(w1, __uint_as_float(q1.z & 0xffff0000u), acc[5]);
                    acc[6] = fmaf(w1, __uint_as_float(q1.w << 16),         acc[6]);
                    acc[7] = fmaf(w1, __uint_as_float(q1.w & 0xffff0000u), acc[7]);
                }
                done += chunk;
            }
        }
        // combine the 4 edge-groups (lanes sharing `sub`)
        #pragma unroll
        for (int i = 0; i < 8; ++i) {
            acc[i] += __shfl_xor(acc[i], 16, 64);
            acc[i] += __shfl_xor(acc[i], 32, 64);
        }
        if (lane < 16) {
            uint4 o;
            o.x = pack_bf16x2(acc[0], acc[1]);
            o.y = pack_bf16x2(acc[2], acc[3]);
            o.z = pack_bf16x2(acc[4], acc[5]);
            o.w = pack_bf16x2(acc[6], acc[7]);
            As4[wid * 16 + q][sub] = o;
        }
    }
    __syncthreads();

    // ---- phase 2: GEMM, waves 2x2 (wr: 32-row group, wc: 64-col group) ----
    const int wr = wid >> 1, wc = wid & 1;
    const int lrow = lane & 15;
    const int lkq  = (lane >> 4);
    const short* As_s = (const short*)&As4[0][0];   // row stride = 136 shorts
    const short* fb   = (const short*)f;

    int grow[2];
    #pragma unroll
    for (int mi = 0; mi < 2; ++mi) {
        int r = tile + wr * 32 + mi * 16 + lrow;
        grow[mi] = (r < N) ? r : (N - 1);
    }

    f32x4 acc2[2][4];
    #pragma unroll
    for (int mi = 0; mi < 2; ++mi)
        #pragma unroll
        for (int nf = 0; nf < 4; ++nf) acc2[mi][nf] = (f32x4){0.f, 0.f, 0.f, 0.f};

    #pragma unroll
    for (int ks = 0; ks < 8; ++ks) {
        bf16x8 a[2], b[4];
        #pragma unroll
        for (int mi = 0; mi < 2; ++mi) {
            if (ks < 4)
                a[mi] = *(const bf16x8*)(As_s + (wr * 32 + mi * 16 + lrow) * 136 + ks * 32 + lkq * 8);
            else
                a[mi] = *(const bf16x8*)(fb + (size_t)grow[mi] * 128 + (ks - 4) * 32 + lkq * 8);
        }
        #pragma unroll
        for (int nf = 0; nf < 4; ++nf)
            b[nf] = Bp[(ks * 8 + (wc * 4 + nf)) * 64 + lane];
        #pragma unroll
        for (int mi = 0; mi < 2; ++mi)
            #pragma unroll
            for (int nf = 0; nf < 4; ++nf)
                acc2[mi][nf] = __builtin_amdgcn_mfma_f32_16x16x32_bf16(a[mi], b[nf], acc2[mi][nf], 0, 0, 0);
    }

    // ---- epilogue ----
    const int crow = (lane >> 4) * 4;
    const int ccol = lane & 15;
    #pragma unroll
    for (int mi = 0; mi < 2; ++mi) {
        #pragma unroll
        for (int nf = 0; nf < 4; ++nf) {
            const int col = wc * 64 + nf * 16 + ccol;
            const float bv = bias[col];
            #pragma unroll
            for (int r = 0; r < 4; ++r) {
                const int row = tile + wr * 32 + mi * 16 + crow + r;
                if (row < N) {
                    float v = acc2[mi][nf][r] + bv;
                    if (RELU) v = fmaxf(v, 0.f);
                    if (OUTF32) outf[(size_t)row * 128 + col] = v;
                    else        outb[(size_t)row * 128 + col] = __float2bfloat16(v);
                }
            }
        }
    }
}

// ---------------- launch ----------------

extern "C" void kernel_launch(void* const* d_in, const int* in_sizes, int n_in,
                              void* d_out, int out_size, void* d_ws, size_t ws_size,
                              hipStream_t stream) {
    const float* x   = (const float*)d_in[0];
    const int*  eidx = (const int*)d_in[1];
    const float* ew  = (const float*)d_in[2];
    const float* w1r = (const float*)d_in[3];
    const float* w1t = (const float*)d_in[4];
    const float* b1  = (const float*)d_in[5];
    const float* w2r = (const float*)d_in[6];
    const float* w2t = (const float*)d_in[7];
    const float* b2  = (const float*)d_in[8];
    const float* w3r = (const float*)d_in[9];
    const float* w3t = (const float*)d_in[10];
    const float* b3  = (const float*)d_in[11];
    float* out = (float*)d_out;

    const int N  = in_sizes[0] / DFEAT;   // 50000
    const int E  = in_sizes[2];           // 800000
    const int NB = (N + 63) / 64;         // 782 buckets

    char* ws = (char*)d_ws;
    size_t off = 0;
    auto alloc = [&](size_t bytes) -> void* {
        off = (off + 255) & ~(size_t)255;
        void* p = ws + off;
        off += bytes;
        return p;
    };
    int*  cursor = (int*)alloc((size_t)NB * 4);
    int*  rowptr = (int*)alloc((size_t)N * 4);
    int*  rowend = (int*)alloc((size_t)N * 4);
    int2* bedges = (int2*)alloc((size_t)NB * BCAP * 8);   // 12.8 MB
    __hip_bfloat16* Bp1 = (__hip_bfloat16*)alloc(32768 * 2);
    __hip_bfloat16* Bp2 = (__hip_bfloat16*)alloc(32768 * 2);
    __hip_bfloat16* Bp3 = (__hip_bfloat16*)alloc(32768 * 2);
    uint* xb   = (uint*)alloc((size_t)N * 64 * 4);
    uint* h1b  = (uint*)alloc((size_t)N * 64 * 4);
    uint* h2b  = (uint*)alloc((size_t)N * 64 * 4);
    (void)ws_size;

    const int* src = eidx;
    const int* dst = eidx + E;

    // merged prep: cvt + weight pack + cursor init
    const int n2 = N * 64;
    const int cvtB = (n2 + 255) / 256;
    const int curB = (NB + 255) / 256;
    prep_all<<<cvtB + 384 + curB, 256, 0, stream>>>(x, xb, n2,
                                                    w1r, w1t, w2r, w2t, w3r, w3t,
                                                    Bp1, Bp2, Bp3, cursor, NB, cvtB);

    // CSR build: bucket scatter + per-bucket counting sort
    bin_scatter<<<(E + 8191) / 8192, 1024, 0, stream>>>(src, dst, ew, cursor, bedges, E, NB);
    bucket_sort<<<NB, 1024, 0, stream>>>(cursor, bedges, rowptr, rowend, N);

    // fused layers
    fused_layer<1, 0><<<NB, 256, 0, stream>>>(xb, rowptr, rowend, bedges, (const bf16x8*)Bp1,
                                              b1, nullptr, (__hip_bfloat16*)h1b, N);
    fused_layer<1, 0><<<NB, 256, 0, stream>>>(h1b, rowptr, rowend, bedges, (const bf16x8*)Bp2,
                                              b2, nullptr, (__hip_bfloat16*)h2b, N);
    fused_layer<0, 1><<<NB, 256, 0, stream>>>(h2b, rowptr, rowend, bedges, (const bf16x8*)Bp3,
                                              b3, out, nullptr, N);
}

// Round 10
// 152.185 us; speedup vs baseline: 1.2446x; 1.0936x over previous
//
#include <hip/hip_runtime.h>
#include <hip/hip_bf16.h>

#define DFEAT   128
#define BCAP    2048         // edge capacity per 64-node bucket (avg ~1024, 32 sigma margin)
#define NB_MAX  1024

typedef __attribute__((ext_vector_type(8))) short bf16x8;
typedef __attribute__((ext_vector_type(4))) float f32x4;
typedef unsigned int uint;

// ---------------- single-pass dst-bucketed edge scatter ----------------
// bucket = dst >> 6. payload: (src | dstLocal<<26, weight_bits)

__global__ __launch_bounds__(1024) void bin_scatter(const int* __restrict__ src,
                                                    const int* __restrict__ dst,
                                                    const float* __restrict__ ew,
                                                    int* __restrict__ cursor,
                                                    int2* __restrict__ bedges,
                                                    int E, int NB) {
    __shared__ int hist[NB_MAX];
    __shared__ int base[NB_MAX];
    const int tid = threadIdx.x;
    for (int b = tid; b < NB; b += 1024) hist[b] = 0;
    __syncthreads();

    int  s[8]; float w[8]; int bk[8]; int dl[8];
    const int i0 = blockIdx.x * 8192 + tid;
    #pragma unroll
    for (int k = 0; k < 8; ++k) {
        int i = i0 + k * 1024;
        if (i < E) {
            s[k] = src[i]; w[k] = ew[i];
            int d = dst[i];
            bk[k] = d >> 6; dl[k] = d & 63;
            atomicAdd(&hist[bk[k]], 1);
        } else bk[k] = -1;
    }
    __syncthreads();
    for (int b = tid; b < NB; b += 1024) {
        int c = hist[b];
        base[b] = (c > 0) ? atomicAdd(&cursor[b], c) : 0;
        hist[b] = 0;                       // reuse as rank counter
    }
    __syncthreads();
    #pragma unroll
    for (int k = 0; k < 8; ++k) {
        if (bk[k] >= 0) {
            int r = atomicAdd(&hist[bk[k]], 1);
            int pos = base[bk[k]] + r;
            if (pos < ((bk[k] + 1) << 11)) {   // overflow guard (never triggers)
                bedges[pos] = make_int2(s[k] | (dl[k] << 26), __float_as_int(w[k]));
            }
        }
    }
}

// ---------------- per-bucket LDS counting sort (in place) + rowptr/rowend ----------------

__global__ __launch_bounds__(1024) void bucket_sort(const int* __restrict__ cursor,
                                                    int2* __restrict__ bedges,
                                                    int* __restrict__ rowptr,
                                                    int* __restrict__ rowend, int N) {
    __shared__ int2 buf[BCAP];                 // 16 KB
    __shared__ int hist[64], pref[64], rank[64];
    const int b = blockIdx.x, tid = threadIdx.x;
    const int base = b << 11;                  // b * BCAP
    const int cnt = cursor[b] - base;

    if (tid < 64) hist[tid] = 0;
    __syncthreads();
    for (int i = tid; i < cnt; i += 1024) {
        int2 e = bedges[base + i];
        buf[i] = e;
        atomicAdd(&hist[((uint)e.x) >> 26], 1);
    }
    __syncthreads();
    if (tid < 64) {
        int v = hist[tid];
        int s = v;
        #pragma unroll
        for (int off = 1; off < 64; off <<= 1) {
            int t = __shfl_up(s, off, 64);
            if (tid >= off) s += t;
        }
        pref[tid] = s - v;                     // exclusive prefix
        rank[tid] = 0;
        int node = b * 64 + tid;
        if (node < N) {
            rowptr[node] = base + (s - v);
            rowend[node] = base + s;
        }
    }
    __syncthreads();
    for (int i = tid; i < cnt; i += 1024) {
        int2 e = buf[i];
        int dl = ((uint)e.x) >> 26;
        int r = atomicAdd(&rank[dl], 1);
        bedges[base + pref[dl] + r] = e;
    }
}

// ---------------- helpers ----------------

__device__ __forceinline__ uint pack_bf16x2(float a, float b) {
    __hip_bfloat16 ba = __float2bfloat16(a);
    __hip_bfloat16 bb = __float2bfloat16(b);
    unsigned short ua = *(unsigned short*)&ba;
    unsigned short ub = *(unsigned short*)&bb;
    return (uint)ua | ((uint)ub << 16);
}

// ---------------- merged prep: cvt (x->bf16) + weight pack x3 + cursor init ----------------
// grid sections: [0, cvtB) cvt; [cvtB, cvtB+384) Bpack; [cvtB+384, ...) cursor init.
// Bpack: Bp[((kstep*8 + nfrag)*64 + lane)*8 + j] = Bcat[kstep*32+(lane>>4)*8+j][nfrag*16+(lane&15)]
//        where Bcat[k][n] = (k<128) ? wrel[n][k] : wroot[n][k-128]

__global__ void prep_all(const float* __restrict__ x, uint* __restrict__ xb, int n2,
                         const float* __restrict__ w1r, const float* __restrict__ w1t,
                         const float* __restrict__ w2r, const float* __restrict__ w2t,
                         const float* __restrict__ w3r, const float* __restrict__ w3t,
                         __hip_bfloat16* __restrict__ Bp1, __hip_bfloat16* __restrict__ Bp2,
                         __hip_bfloat16* __restrict__ Bp3,
                         int* __restrict__ cursor, int NB, int cvtB) {
    const int b = blockIdx.x, tid = threadIdx.x;
    if (b < cvtB) {
        int i = b * 256 + tid;
        if (i < n2) {
            float2 v = ((const float2*)x)[i];
            xb[i] = pack_bf16x2(v.x, v.y);
        }
    } else if (b < cvtB + 384) {
        const int b2 = b - cvtB;
        const int g = b2 >> 7;                       // layer 0,1,2
        const int idx = (b2 & 127) * 256 + tid;      // 0..32767
        const float* wrel  = (g == 0) ? w1r : (g == 1) ? w2r : w3r;
        const float* wroot = (g == 0) ? w1t : (g == 1) ? w2t : w3t;
        __hip_bfloat16* Bp = (g == 0) ? Bp1 : (g == 1) ? Bp2 : Bp3;
        int j     = idx & 7;
        int lane  = (idx >> 3) & 63;
        int nfrag = (idx >> 9) & 7;
        int kstep = idx >> 12;
        int k = kstep * 32 + (lane >> 4) * 8 + j;
        int n = nfrag * 16 + (lane & 15);
        float v = (k < 128) ? wrel[n * 128 + k] : wroot[n * 128 + (k - 128)];
        Bp[idx] = __float2bfloat16(v);
    } else {
        int i = (b - cvtB - 384) * 256 + tid;
        if (i < NB) cursor[i] = i * BCAP;
    }
}

// ---------------- fused layer: per-bucket agg -> LDS -> MFMA GEMM (8 waves) ----------
// Block = one 64-node bucket, 512 threads (8 waves).
// Phase 1: wave w aggregates nodes tile+w*8 .. +7 sequentially; 16 lanes/edge
//   (grp=lane>>4 picks edge-of-quad, sub=lane&15 picks 16B row slice); result -> LDS bf16.
// Phase 2: C[64,128] = [aggLDS | root][64,256] @ Bcat[256,128] + bias via MFMA;
//   waves 2x4: wr=wid>>2 (32 rows), wc=wid&3 (32 cols), each wave 2x2 frags.

template<int RELU, int OUTF32>
__global__ __launch_bounds__(512) void fused_layer(const uint* __restrict__ f,
                                                   const int* __restrict__ rowptr,
                                                   const int* __restrict__ rowend,
                                                   const int2* __restrict__ bedges,
                                                   const bf16x8* __restrict__ Bp,
                                                   const float* __restrict__ bias,
                                                   float* __restrict__ outf,
                                                   __hip_bfloat16* __restrict__ outb,
                                                   int N) {
    __shared__ uint4 As4[64][17];                  // 17408 B, row stride 272B
    const int tid  = threadIdx.x;
    const int lane = tid & 63, wid = tid >> 6;     // wid 0..7
    const int grp  = lane >> 4;
    const int sub  = lane & 15;
    const int tile = blockIdx.x * 64;
    const uint4* f4 = (const uint4*)f;

    // prefetch this wave's 8 rowptr/rowend (lane-parallel, one round-trip)
    const int pn = tile + wid * 8 + (lane & 7);
    int rp = 0, re = 0;
    if (lane < 8 && pn < N) { rp = rowptr[pn]; re = rowend[pn]; }

    // ---- phase 1: aggregate 8 nodes per wave ----
    for (int q = 0; q < 8; ++q) {
        const int node = tile + wid * 8 + q;
        const int beg = __builtin_amdgcn_readlane(rp, q);
        const int end = __builtin_amdgcn_readlane(re, q);
        const int deg = end - beg;

        float acc[8];
        #pragma unroll
        for (int i = 0; i < 8; ++i) acc[i] = 0.f;

        if (node < N) {
            int done = 0;
            while (done < deg) {
                const int chunk = min(deg - done, 64);
                int2 e = bedges[beg + done + min(lane, chunk - 1)];
                const int vsrc = e.x & 0x03FFFFFF;
                const int vwb  = (lane < chunk) ? e.y : 0;   // 0 bits == 0.0f
                const int iters = (chunk + 7) & ~7;
                for (int j = 0; j < iters; j += 8) {
                    const int   s0 = __shfl(vsrc, j + grp, 64);
                    const float w0 = __int_as_float(__shfl(vwb, j + grp, 64));
                    const int   s1 = __shfl(vsrc, j + 4 + grp, 64);
                    const float w1 = __int_as_float(__shfl(vwb, j + 4 + grp, 64));
                    const uint4 q0 = f4[(size_t)s0 * 16 + sub];
                    const uint4 q1 = f4[(size_t)s1 * 16 + sub];
                    acc[0] = fmaf(w0, __uint_as_float(q0.x << 16),         acc[0]);
                    acc[1] = fmaf(w0, __uint_as_float(q0.x & 0xffff0000u), acc[1]);
                    acc[2] = fmaf(w0, __uint_as_float(q0.y << 16),         acc[2]);
                    acc[3] = fmaf(w0, __uint_as_float(q0.y & 0xffff0000u), acc[3]);
                    acc[4] = fmaf(w0, __uint_as_float(q0.z << 16),         acc[4]);
                    acc[5] = fmaf(w0, __uint_as_float(q0.z & 0xffff0000u), acc[5]);
                    acc[6] = fmaf(w0, __uint_as_float(q0.w << 16),         acc[6]);
                    acc[7] = fmaf(w0, __uint_as_float(q0.w & 0xffff0000u), acc[7]);
                    acc[0] = fmaf(w1, __uint_as_float(q1.x << 16),         acc[0]);
                    acc[1] = fmaf(w1, __uint_as_float(q1.x & 0xffff0000u), acc[1]);
                    acc[2] = fmaf(w1, __uint_as_float(q1.y << 16),         acc[2]);
                    acc[3] = fmaf(w1, __uint_as_float(q1.y & 0xffff0000u), acc[3]);
                    acc[4] = fmaf(w1, __uint_as_float(q1.z << 16),         acc[4]);
                    acc[5] = fmaf(w1, __uint_as_float(q1.z & 0xffff0000u), acc[5]);
                    acc[6] = fmaf(w1, __uint_as_float(q1.w << 16),         acc[6]);
                    acc[7] = fmaf(w1, __uint_as_float(q1.w & 0xffff0000u), acc[7]);
                }
                done += chunk;
            }
        }
        // combine the 4 edge-groups (lanes sharing `sub`)
        #pragma unroll
        for (int i = 0; i < 8; ++i) {
            acc[i] += __shfl_xor(acc[i], 16, 64);
            acc[i] += __shfl_xor(acc[i], 32, 64);
        }
        if (lane < 16) {
            uint4 o;
            o.x = pack_bf16x2(acc[0], acc[1]);
            o.y = pack_bf16x2(acc[2], acc[3]);
            o.z = pack_bf16x2(acc[4], acc[5]);
            o.w = pack_bf16x2(acc[6], acc[7]);
            As4[wid * 8 + q][sub] = o;
        }
    }
    __syncthreads();

    // ---- phase 2: GEMM, waves 2x4 (wr: 32-row group, wc: 32-col group) ----
    const int wr = wid >> 2, wc = wid & 3;
    const int lrow = lane & 15;
    const int lkq  = (lane >> 4);
    const short* As_s = (const short*)&As4[0][0];   // row stride = 136 shorts
    const short* fb   = (const short*)f;

    int grow[2];
    #pragma unroll
    for (int mi = 0; mi < 2; ++mi) {
        int r = tile + wr * 32 + mi * 16 + lrow;
        grow[mi] = (r < N) ? r : (N - 1);
    }

    f32x4 acc2[2][2];
    #pragma unroll
    for (int mi = 0; mi < 2; ++mi)
        #pragma unroll
        for (int nf = 0; nf < 2; ++nf) acc2[mi][nf] = (f32x4){0.f, 0.f, 0.f, 0.f};

    #pragma unroll
    for (int ks = 0; ks < 8; ++ks) {
        bf16x8 a[2], b[2];
        #pragma unroll
        for (int mi = 0; mi < 2; ++mi) {
            if (ks < 4)
                a[mi] = *(const bf16x8*)(As_s + (wr * 32 + mi * 16 + lrow) * 136 + ks * 32 + lkq * 8);
            else
                a[mi] = *(const bf16x8*)(fb + (size_t)grow[mi] * 128 + (ks - 4) * 32 + lkq * 8);
        }
        #pragma unroll
        for (int nf = 0; nf < 2; ++nf)
            b[nf] = Bp[(ks * 8 + (wc * 2 + nf)) * 64 + lane];
        #pragma unroll
        for (int mi = 0; mi < 2; ++mi)
            #pragma unroll
            for (int nf = 0; nf < 2; ++nf)
                acc2[mi][nf] = __builtin_amdgcn_mfma_f32_16x16x32_bf16(a[mi], b[nf], acc2[mi][nf], 0, 0, 0);
    }

    // ---- epilogue ----
    const int crow = (lane >> 4) * 4;
    const int ccol = lane & 15;
    #pragma unroll
    for (int mi = 0; mi < 2; ++mi) {
        #pragma unroll
        for (int nf = 0; nf < 2; ++nf) {
            const int col = wc * 32 + nf * 16 + ccol;
            const float bv = bias[col];
            #pragma unroll
            for (int r = 0; r < 4; ++r) {
                const int row = tile + wr * 32 + mi * 16 + crow + r;
                if (row < N) {
                    float v = acc2[mi][nf][r] + bv;
                    if (RELU) v = fmaxf(v, 0.f);
                    if (OUTF32) outf[(size_t)row * 128 + col] = v;
                    else        outb[(size_t)row * 128 + col] = __float2bfloat16(v);
                }
            }
        }
    }
}

// ---------------- launch ----------------

extern "C" void kernel_launch(void* const* d_in, const int* in_sizes, int n_in,
                              void* d_out, int out_size, void* d_ws, size_t ws_size,
                              hipStream_t stream) {
    const float* x   = (const float*)d_in[0];
    const int*  eidx = (const int*)d_in[1];
    const float* ew  = (const float*)d_in[2];
    const float* w1r = (const float*)d_in[3];
    const float* w1t = (const float*)d_in[4];
    const float* b1  = (const float*)d_in[5];
    const float* w2r = (const float*)d_in[6];
    const float* w2t = (const float*)d_in[7];
    const float* b2  = (const float*)d_in[8];
    const float* w3r = (const float*)d_in[9];
    const float* w3t = (const float*)d_in[10];
    const float* b3  = (const float*)d_in[11];
    float* out = (float*)d_out;

    const int N  = in_sizes[0] / DFEAT;   // 50000
    const int E  = in_sizes[2];           // 800000
    const int NB = (N + 63) / 64;         // 782 buckets

    char* ws = (char*)d_ws;
    size_t off = 0;
    auto alloc = [&](size_t bytes) -> void* {
        off = (off + 255) & ~(size_t)255;
        void* p = ws + off;
        off += bytes;
        return p;
    };
    int*  cursor = (int*)alloc((size_t)NB * 4);
    int*  rowptr = (int*)alloc((size_t)N * 4);
    int*  rowend = (int*)alloc((size_t)N * 4);
    int2* bedges = (int2*)alloc((size_t)NB * BCAP * 8);   // 12.8 MB
    __hip_bfloat16* Bp1 = (__hip_bfloat16*)alloc(32768 * 2);
    __hip_bfloat16* Bp2 = (__hip_bfloat16*)alloc(32768 * 2);
    __hip_bfloat16* Bp3 = (__hip_bfloat16*)alloc(32768 * 2);
    uint* xb   = (uint*)alloc((size_t)N * 64 * 4);
    uint* h1b  = (uint*)alloc((size_t)N * 64 * 4);
    uint* h2b  = (uint*)alloc((size_t)N * 64 * 4);
    (void)ws_size;

    const int* src = eidx;
    const int* dst = eidx + E;

    // merged prep: cvt + weight pack + cursor init
    const int n2 = N * 64;
    const int cvtB = (n2 + 255) / 256;
    const int curB = (NB + 255) / 256;
    prep_all<<<cvtB + 384 + curB, 256, 0, stream>>>(x, xb, n2,
                                                    w1r, w1t, w2r, w2t, w3r, w3t,
                                                    Bp1, Bp2, Bp3, cursor, NB, cvtB);

    // CSR build: bucket scatter + per-bucket counting sort
    bin_scatter<<<(E + 8191) / 8192, 1024, 0, stream>>>(src, dst, ew, cursor, bedges, E, NB);
    bucket_sort<<<NB, 1024, 0, stream>>>(cursor, bedges, rowptr, rowend, N);

    // fused layers
    fused_layer<1, 0><<<NB, 512, 0, stream>>>(xb, rowptr, rowend, bedges, (const bf16x8*)Bp1,
                                              b1, nullptr, (__hip_bfloat16*)h1b, N);
    fused_layer<1, 0><<<NB, 512, 0, stream>>>(h1b, rowptr, rowend, bedges, (const bf16x8*)Bp2,
                                              b2, nullptr, (__hip_bfloat16*)h2b, N);
    fused_layer<0, 1><<<NB, 512, 0, stream>>>(h2b, rowptr, rowend, bedges, (const bf16x8*)Bp3,
                                              b3, out, nullptr, N);
}